// Round 9
// baseline (261.608 us; speedup 1.0000x reference)
//
#include <hip/hip_runtime.h>
#include <hip/hip_fp16.h>
#include <hip/hip_cooperative_groups.h>

namespace cg = cooperative_groups;

// GCNConv (PyG semantics) + eval-dropout(identity) + ReLU, fp32 in/out.
// N=100000 nodes, E=1600000 edges, D=64.
//
//  Kernel 1 (k_gemm): zero gcur + xw_h = fp16(x@W) via mfma_f32_16x16x32_bf16
//     (no dis scaling -> independent of edge processing).
//  Kernel 2 (k_fused, cooperative, 256 blocks x 1024 = 1/CU):
//    A: partition edges -> packed=(row<<8)|(col&255) per 256-node bucket
//       (LDS hist + one global claim atomic per (block,bucket)); grid.sync
//    B: per-bucket hist (packed cached in regs) -> dis[n]=rsqrt(deg+1); grid.sync
//    C: scan + register-sort into LDS srt, gather with per-edge dis[r],
//       fused self-loop + bias + ReLU.

#define D 64
#define BW 256            // dest nodes per bucket
#define MAXB 512          // >= NBUCK (391)
#define CAP 6144          // per-bucket edge capacity (mean 4092, +32 sigma)
#define RPT 6             // CAP / BT
#define GRID 256          // coop grid: one block per CU
#define BT 1024
#define EPT 7             // ceil(E/GRID/BT)

typedef __attribute__((ext_vector_type(8))) short bf16x8;
typedef __attribute__((ext_vector_type(4))) float f32x4;

__device__ __forceinline__ unsigned short f2bf(float f) {   // RNE fp32->bf16
    unsigned u = __float_as_uint(f);
    u += 0x7FFFu + ((u >> 16) & 1u);
    return (unsigned short)(u >> 16);
}

// ---- 1. MFMA GEMM (unscaled) + zero prologue -------------------------------
// A: m=lane&15, k=quad*8+j. C/D: col=lane&15, row=quad*4+reg (m89/m91).
__global__ __launch_bounds__(256, 4)
void k_gemm(const float* __restrict__ x, const float* __restrict__ W,
            unsigned short* __restrict__ xw_h, int* __restrict__ zero_base,
            int nzero, int N) {
    int zi = blockIdx.x * 256 + threadIdx.x;
    if (zi < nzero) zero_base[zi] = 0;
    __shared__ float Ws[64 * 64];
    int tid = threadIdx.x;
    for (int i = tid; i < 4096; i += 256) Ws[i] = W[i];
    __syncthreads();
    int lane = tid & 63, wv = tid >> 6;
    int m = lane & 15, quad = lane >> 4;
    bf16x8 Bf[4][2];
#pragma unroll
    for (int t = 0; t < 4; ++t)
#pragma unroll
        for (int s = 0; s < 2; ++s) {
            bf16x8 f;
#pragma unroll
            for (int j = 0; j < 8; ++j)
                f[j] = (short)f2bf(Ws[(s * 32 + quad * 8 + j) * 64 + t * 16 + m]);
            Bf[t][s] = f;
        }
    int mt = blockIdx.x * 4 + wv;           // M-tile
    int row0 = mt * 16;
    if (row0 >= N) return;
    const float* xr = x + (size_t)(row0 + m) * 64 + quad * 8;
    float4 a0 = *(const float4*)(xr);
    float4 a1 = *(const float4*)(xr + 4);
    float4 a2 = *(const float4*)(xr + 32);
    float4 a3 = *(const float4*)(xr + 36);
    bf16x8 A0, A1;
    A0[0] = (short)f2bf(a0.x); A0[1] = (short)f2bf(a0.y);
    A0[2] = (short)f2bf(a0.z); A0[3] = (short)f2bf(a0.w);
    A0[4] = (short)f2bf(a1.x); A0[5] = (short)f2bf(a1.y);
    A0[6] = (short)f2bf(a1.z); A0[7] = (short)f2bf(a1.w);
    A1[0] = (short)f2bf(a2.x); A1[1] = (short)f2bf(a2.y);
    A1[2] = (short)f2bf(a2.z); A1[3] = (short)f2bf(a2.w);
    A1[4] = (short)f2bf(a3.x); A1[5] = (short)f2bf(a3.y);
    A1[6] = (short)f2bf(a3.z); A1[7] = (short)f2bf(a3.w);
    f32x4 acc[4];
#pragma unroll
    for (int t = 0; t < 4; ++t) {
        acc[t] = (f32x4){0.f, 0.f, 0.f, 0.f};
        acc[t] = __builtin_amdgcn_mfma_f32_16x16x32_bf16(A0, Bf[t][0], acc[t], 0, 0, 0);
        acc[t] = __builtin_amdgcn_mfma_f32_16x16x32_bf16(A1, Bf[t][1], acc[t], 0, 0, 0);
    }
#pragma unroll
    for (int t = 0; t < 4; ++t)
#pragma unroll
        for (int r = 0; r < 4; ++r) {
            int grow = row0 + quad * 4 + r;
            int gcol = t * 16 + m;
            xw_h[(size_t)grow * 64 + gcol] =
                __half_as_ushort(__float2half(acc[t][r]));
        }
}

// ---- 2. cooperative fused partition + dis + gather -------------------------
__global__ __launch_bounds__(BT, 4)
void k_fused(const int* __restrict__ row, const int* __restrict__ col,
             int* __restrict__ gcur, int* __restrict__ packed,
             float* __restrict__ disg, const uint2* __restrict__ xwh,
             const float* __restrict__ bias, float4* __restrict__ out4,
             int E, int N, int NBUCK) {
    __shared__ int lhp[MAXB];
    __shared__ int basep[MAXB];
    __shared__ int lhb[2][BW];
    __shared__ int stt[BW], cur[BW];
    __shared__ int wsum[4];
    __shared__ int srtL[CAP];

    cg::grid_group grid = cg::this_grid();
    int tid = threadIdx.x;
    int bk  = (int)blockIdx.x;

    // ======== phase A: partition ========
    for (int i = tid; i < NBUCK; i += BT) lhp[i] = 0;
    __syncthreads();
    int epb = (E + GRID - 1) / GRID;
    int e0 = bk * epb;
    int eend = min(e0 + epb, E);
    int rr[EPT], cc[EPT], pp[EPT];
#pragma unroll
    for (int i = 0; i < EPT; ++i) {
        int e = e0 + i * BT + tid;
        if (e < eend) {
            cc[i] = col[e]; rr[i] = row[e];
            pp[i] = atomicAdd(&lhp[cc[i] >> 8], 1);
        } else cc[i] = -1;
    }
    __syncthreads();
    int rot = (int)((bk * 97u) % (unsigned)NBUCK);
    for (int j = tid; j < NBUCK; j += BT) {
        int bu = j + rot; if (bu >= NBUCK) bu -= NBUCK;
        int h = lhp[bu];
        if (h > 0) basep[bu] = atomicAdd(&gcur[bu * 32], h);
    }
    __syncthreads();
#pragma unroll
    for (int i = 0; i < EPT; ++i) {
        if (cc[i] >= 0) {
            int bu = cc[i] >> 8;
            int pos = basep[bu] + pp[i];
            if (pos < CAP)
                packed[(size_t)bu * CAP + pos] = (rr[i] << 8) | (cc[i] & 255);
        }
    }
    grid.sync();

    // ======== phase B: per-bucket hist + dis (packed cached in regs) ========
    int rv[2][RPT];
#pragma unroll
    for (int p = 0; p < 2; ++p) {
        int b = bk + p * GRID;
        if (b < NBUCK) {
            if (tid < BW) lhb[p][tid] = 0;
            __syncthreads();
            int sz = min(gcur[b * 32], CAP);
            const int* pk = packed + (size_t)b * CAP;
#pragma unroll
            for (int i = 0; i < RPT; ++i) {
                int idx = i * BT + tid;
                int v = (idx < sz) ? pk[idx] : -1;
                rv[p][i] = v;
                if (v >= 0) atomicAdd(&lhb[p][v & 255], 1);
            }
            __syncthreads();
            if (tid < BW) {
                int n = b * BW + tid;
                if (n < N) disg[n] = rsqrtf((float)(lhb[p][tid] + 1));
            }
        }
    }
    grid.sync();

    // ======== phase C: scan + register-sort + gather ========
    int lane = tid & 63, wv = tid >> 6;
    int q = lane >> 4;       // edge subset 0..3
    int l = lane & 15;       // 8-byte chunk: dims 4l..4l+3
    const float4 bb = ((const float4*)bias)[l];
#define ADDS(h, ww)                                                         \
    {                                                                       \
        __half2 h0 = *(__half2*)&(h).x, h1 = *(__half2*)&(h).y;             \
        float2 f0 = __half22float2(h0), f1 = __half22float2(h1);            \
        acc.x = fmaf((ww), f0.x, acc.x); acc.y = fmaf((ww), f0.y, acc.y);   \
        acc.z = fmaf((ww), f1.x, acc.z); acc.w = fmaf((ww), f1.y, acc.w);   \
    }
    for (int p = 0; p < 2; ++p) {
        int b = bk + p * GRID;
        if (b >= NBUCK) break;
        __syncthreads();   // protect stt/cur/srtL reuse across passes
        int v = (tid < BW) ? lhb[p][tid] : 0;
        int s = v;
#pragma unroll
        for (int off = 1; off < 64; off <<= 1) {
            int u = __shfl_up(s, off);
            if (lane >= off) s += u;
        }
        if (tid < BW && lane == 63) wsum[wv] = s;
        __syncthreads();
        if (tid < BW) {
            int woff = 0;
            for (int w = 0; w < 4; ++w) woff += (w < wv) ? wsum[w] : 0;
            int st = woff + s - v;
            stt[tid] = st; cur[tid] = st;
        }
        __syncthreads();
#pragma unroll
        for (int i = 0; i < RPT; ++i) {
            int pv = rv[p][i];
            if (pv >= 0) {
                int pos = atomicAdd(&cur[pv & 255], 1);
                srtL[pos] = pv >> 8;
            }
        }
        __syncthreads();
        // gather: 16 waves x 16 nodes; 16 lanes x 8B, 4 edge slots, 4-deep
        for (int nn = wv * 16; nn < wv * 16 + 16; ++nn) {
            int node = b * BW + nn;
            if (node >= N) break;
            int k = lhb[p][nn], s0 = stt[nn];
            float dn = rsqrtf((float)(k + 1));
            float4 acc = make_float4(0.f, 0.f, 0.f, 0.f);
            if (q == 0) {   // self-loop: dis[c]*xw[c]
                uint2 hs = xwh[(size_t)node * 16 + l];
                ADDS(hs, dn);
            }
            int j = q;
            for (; j + 12 < k; j += 16) {
                int r0 = srtL[s0 + j];
                int r1 = srtL[s0 + j + 4];
                int r2 = srtL[s0 + j + 8];
                int r3 = srtL[s0 + j + 12];
                float w0 = disg[r0], w1 = disg[r1], w2 = disg[r2], w3 = disg[r3];
                uint2 va = xwh[(size_t)r0 * 16 + l];
                uint2 vb = xwh[(size_t)r1 * 16 + l];
                uint2 vc = xwh[(size_t)r2 * 16 + l];
                uint2 vd = xwh[(size_t)r3 * 16 + l];
                ADDS(va, w0); ADDS(vb, w1); ADDS(vc, w2); ADDS(vd, w3);
            }
            for (; j < k; j += 4) {
                int r = srtL[s0 + j];
                float wr = disg[r];
                uint2 ve = xwh[(size_t)r * 16 + l];
                ADDS(ve, wr);
            }
#pragma unroll
            for (int mm = 16; mm < 64; mm <<= 1) {
                acc.x += __shfl_xor(acc.x, mm);
                acc.y += __shfl_xor(acc.y, mm);
                acc.z += __shfl_xor(acc.z, mm);
                acc.w += __shfl_xor(acc.w, mm);
            }
            if (q == 0) {
                float4 o;
                o.x = fmaxf(fmaf(dn, acc.x, bb.x), 0.f);
                o.y = fmaxf(fmaf(dn, acc.y, bb.y), 0.f);
                o.z = fmaxf(fmaf(dn, acc.z, bb.z), 0.f);
                o.w = fmaxf(fmaf(dn, acc.w, bb.w), 0.f);
                out4[(size_t)node * 16 + l] = o;
            }
        }
    }
#undef ADDS
}

extern "C" void kernel_launch(void* const* d_in, const int* in_sizes, int n_in,
                              void* d_out, int out_size, void* d_ws, size_t ws_size,
                              hipStream_t stream) {
    const float* x    = (const float*)d_in[0];
    const int*   ei   = (const int*)d_in[1];   // int32 (JAX demotes int64)
    const float* W    = (const float*)d_in[2];
    const float* bias = (const float*)d_in[3];
    float* out = (float*)d_out;

    int N = in_sizes[0] / D;
    int E = in_sizes[1] / 2;
    const int* rowp = ei;       // edge_index[0] = sources
    const int* colp = ei + E;   // edge_index[1] = destinations

    int NBUCK = (N + BW - 1) / BW;             // 391
    const int NT = (N + 15) / 16;              // 6250 M-tiles

    char* ws = (char*)d_ws;
    size_t off = 0;
    unsigned short* xw_h = (unsigned short*)(ws + off);
    off += (size_t)N * D * sizeof(unsigned short);                     // 12.8 MB
    int* packed = (int*)(ws + off); off += (size_t)NBUCK * CAP * sizeof(int); // 9.6 MB
    int* gcur   = (int*)(ws + off); off += (size_t)NBUCK * 32 * sizeof(int);  // 50 KB
    float* disg = (float*)(ws + off); off += (size_t)N * sizeof(float);

    int nzero = NBUCK * 32;

    k_gemm<<<(NT + 3) / 4, 256, 0, stream>>>(x, W, xw_h, gcur, nzero, N);

    const uint2* xwh_c = (const uint2*)xw_h;
    float4* outp = (float4*)out;
    void* args[] = {(void*)&rowp, (void*)&colp, (void*)&gcur, (void*)&packed,
                    (void*)&disg, (void*)&xwh_c, (void*)&bias, (void*)&outp,
                    (void*)&E, (void*)&N, (void*)&NBUCK};
    (void)hipLaunchCooperativeKernel((void*)k_fused, dim3(GRID), dim3(BT), args, 0, stream);
}

// Round 10
// 175.433 us; speedup vs baseline: 1.4912x; 1.4912x over previous
//
#include <hip/hip_runtime.h>
#include <hip/hip_fp16.h>

// GCNConv (PyG semantics) + eval-dropout(identity) + ReLU, fp32 in/out.
// N=100000 nodes, E=1600000 edges, D=64.
//
// Atomic-free store+scan partition (no contended device atomics):
//  1. k_gemm: xw_h = fp16(x@W) (unscaled) via mfma_f32_16x16x32_bf16.
//  2. k_hist1: per-block LDS hist -> hist[bu*NB1+blk] (pure stores,
//     exclusively-owned slots -- zero global atomics).
//  3-5. exscan over L=NBUCK*NB1 ints -> histS (exact global positions).
//  6. k_scatter1: LDS cursors init from histS -> packed dense array,
//     packed=(row<<8)|(col&255), runs semi-coalesced.
//  7. k_dis: per-bucket per-node hist from packed -> disg=rsqrt(deg+1).
//  8. k_gather: per bucket: LDS hist+scan+sort, register gather with
//     per-edge disg[r] weights, fused self-loop + bias + ReLU.

#define D 64
#define BW 256             // dest nodes per bucket
#define CAP 6144           // LDS sort capacity (bucket mean 4092, +32 sigma)
#define PART_T 256
#define EPB 4096           // edges per hist/scatter block
#define SCAN_CHUNK 1024

typedef __attribute__((ext_vector_type(8))) short bf16x8;
typedef __attribute__((ext_vector_type(4))) float f32x4;

__device__ __forceinline__ unsigned short f2bf(float f) {   // RNE fp32->bf16
    unsigned u = __float_as_uint(f);
    u += 0x7FFFu + ((u >> 16) & 1u);
    return (unsigned short)(u >> 16);
}

// ---- 1. MFMA GEMM (unscaled) -----------------------------------------------
// A: m=lane&15, k=quad*8+j. C/D: col=lane&15, row=quad*4+reg (m89/m91).
__global__ __launch_bounds__(256, 4)
void k_gemm(const float* __restrict__ x, const float* __restrict__ W,
            unsigned short* __restrict__ xw_h, int N) {
    __shared__ float Ws[64 * 64];
    int tid = threadIdx.x;
    for (int i = tid; i < 4096; i += 256) Ws[i] = W[i];
    __syncthreads();
    int lane = tid & 63, wv = tid >> 6;
    int m = lane & 15, quad = lane >> 4;
    bf16x8 Bf[4][2];
#pragma unroll
    for (int t = 0; t < 4; ++t)
#pragma unroll
        for (int s = 0; s < 2; ++s) {
            bf16x8 f;
#pragma unroll
            for (int j = 0; j < 8; ++j)
                f[j] = (short)f2bf(Ws[(s * 32 + quad * 8 + j) * 64 + t * 16 + m]);
            Bf[t][s] = f;
        }
    int row0 = (blockIdx.x * 4 + wv) * 16;
    if (row0 >= N) return;
    const float* xr = x + (size_t)(row0 + m) * 64 + quad * 8;
    float4 a0 = *(const float4*)(xr);
    float4 a1 = *(const float4*)(xr + 4);
    float4 a2 = *(const float4*)(xr + 32);
    float4 a3 = *(const float4*)(xr + 36);
    bf16x8 A0, A1;
    A0[0] = (short)f2bf(a0.x); A0[1] = (short)f2bf(a0.y);
    A0[2] = (short)f2bf(a0.z); A0[3] = (short)f2bf(a0.w);
    A0[4] = (short)f2bf(a1.x); A0[5] = (short)f2bf(a1.y);
    A0[6] = (short)f2bf(a1.z); A0[7] = (short)f2bf(a1.w);
    A1[0] = (short)f2bf(a2.x); A1[1] = (short)f2bf(a2.y);
    A1[2] = (short)f2bf(a2.z); A1[3] = (short)f2bf(a2.w);
    A1[4] = (short)f2bf(a3.x); A1[5] = (short)f2bf(a3.y);
    A1[6] = (short)f2bf(a3.z); A1[7] = (short)f2bf(a3.w);
    f32x4 acc[4];
#pragma unroll
    for (int t = 0; t < 4; ++t) {
        acc[t] = (f32x4){0.f, 0.f, 0.f, 0.f};
        acc[t] = __builtin_amdgcn_mfma_f32_16x16x32_bf16(A0, Bf[t][0], acc[t], 0, 0, 0);
        acc[t] = __builtin_amdgcn_mfma_f32_16x16x32_bf16(A1, Bf[t][1], acc[t], 0, 0, 0);
    }
#pragma unroll
    for (int t = 0; t < 4; ++t)
#pragma unroll
        for (int r = 0; r < 4; ++r)
            xw_h[(size_t)(row0 + quad * 4 + r) * 64 + t * 16 + m] =
                __half_as_ushort(__float2half(acc[t][r]));
}

// ---- 2. per-block histogram: pure stores to exclusively-owned slots --------
__global__ void k_hist1(const int* __restrict__ col, int* __restrict__ hist,
                        int E, int NB1, int NBUCK) {
    extern __shared__ int lhist[];          // NBUCK ints
    int bk = blockIdx.x;
    for (int bu = threadIdx.x; bu < NBUCK; bu += PART_T) lhist[bu] = 0;
    __syncthreads();
    int base = bk * EPB;
#pragma unroll 4
    for (int i = threadIdx.x; i < EPB; i += PART_T) {
        int e = base + i;
        if (e < E) atomicAdd(&lhist[col[e] >> 8], 1);   // LDS only
    }
    __syncthreads();
    for (int bu = threadIdx.x; bu < NBUCK; bu += PART_T)
        hist[bu * NB1 + bk] = lhist[bu];
}

// ---- 3-5. exscan over L ints -----------------------------------------------
__global__ void k_blocksum(const int* __restrict__ src, int* __restrict__ partial, int L) {
    int base = blockIdx.x * SCAN_CHUNK;
    int s = 0;
    for (int i = threadIdx.x; i < SCAN_CHUNK; i += 256) {
        int idx = base + i;
        s += (idx < L) ? src[idx] : 0;
    }
#pragma unroll
    for (int off = 32; off > 0; off >>= 1) s += __shfl_down(s, off);
    __shared__ int ws[4];
    if ((threadIdx.x & 63) == 0) ws[threadIdx.x >> 6] = s;
    __syncthreads();
    if (threadIdx.x == 0) partial[blockIdx.x] = ws[0] + ws[1] + ws[2] + ws[3];
}

__global__ void k_scan_partials(int* __restrict__ partial, int P) {  // P <= 256
    __shared__ int wtot[4];
    int i = threadIdx.x;
    int v = (i < P) ? partial[i] : 0;
    int lane = i & 63, wv = i >> 6;
    int s = v;
#pragma unroll
    for (int off = 1; off < 64; off <<= 1) {
        int t = __shfl_up(s, off);
        if (lane >= off) s += t;
    }
    if (lane == 63) wtot[wv] = s;
    __syncthreads();
    int woff = 0;
    for (int w = 0; w < 4; ++w) woff += (w < wv) ? wtot[w] : 0;
    if (i < P) partial[i] = woff + s - v;
}

__global__ void k_scan_excl(const int* __restrict__ src, const int* __restrict__ partial,
                            int* __restrict__ dst, int L) {
    __shared__ int wsum[4];
    int lane = threadIdx.x & 63, wv = threadIdx.x >> 6;
    int base = blockIdx.x * SCAN_CHUNK + threadIdx.x * 4;
    int v0 = (base + 0 < L) ? src[base + 0] : 0;
    int v1 = (base + 1 < L) ? src[base + 1] : 0;
    int v2 = (base + 2 < L) ? src[base + 2] : 0;
    int v3 = (base + 3 < L) ? src[base + 3] : 0;
    int t = v0 + v1 + v2 + v3;
    int s = t;
#pragma unroll
    for (int off = 1; off < 64; off <<= 1) {
        int u = __shfl_up(s, off);
        if (lane >= off) s += u;
    }
    if (lane == 63) wsum[wv] = s;
    __syncthreads();
    int woff = 0;
    for (int w = 0; w < 4; ++w) woff += (w < wv) ? wsum[w] : 0;
    int excl = partial[blockIdx.x] + woff + (s - t);
    if (base + 0 < L) dst[base + 0] = excl;
    if (base + 1 < L) dst[base + 1] = excl + v0;
    if (base + 2 < L) dst[base + 2] = excl + v0 + v1;
    if (base + 3 < L) dst[base + 3] = excl + v0 + v1 + v2;
}

// ---- 6. scatter into dense packed at exact positions (no global atomics) ---
__global__ void k_scatter1(const int* __restrict__ row, const int* __restrict__ col,
                           const int* __restrict__ histS, int* __restrict__ packed,
                           int E, int NB1, int NBUCK) {
    extern __shared__ int cur[];            // NBUCK ints
    int bk = blockIdx.x;
    for (int bu = threadIdx.x; bu < NBUCK; bu += PART_T)
        cur[bu] = histS[bu * NB1 + bk];     // this block's exact start in bucket bu
    __syncthreads();
    int base = bk * EPB;
#pragma unroll 4
    for (int i = threadIdx.x; i < EPB; i += PART_T) {
        int e = base + i;
        if (e < E) {
            int c = col[e], r = row[e];
            int pos = atomicAdd(&cur[c >> 8], 1);   // LDS only
            packed[pos] = (r << 8) | (c & 255);
        }
    }
}

// ---- 7. per-node degree -> dis ---------------------------------------------
__global__ void k_dis(const int* __restrict__ histS, const int* __restrict__ packed,
                      float* __restrict__ disg, int E, int NB1, int NBUCK, int N) {
    __shared__ int lh[BW];
    int b = blockIdx.x;
    int lo = histS[b * NB1];
    int hi = (b == NBUCK - 1) ? E : histS[(b + 1) * NB1];
    lh[threadIdx.x] = 0;
    __syncthreads();
    for (int i = lo + threadIdx.x; i < hi; i += BW)
        atomicAdd(&lh[packed[i] & 255], 1);
    __syncthreads();
    int n = b * BW + threadIdx.x;
    if (n < N) disg[n] = rsqrtf((float)(lh[threadIdx.x] + 1));
}

// ---- 8. fused sort + gather: one 1024-thr block per bucket -----------------
__global__ __launch_bounds__(1024, 8)
void k_gather(const int* __restrict__ histS, const int* __restrict__ packed,
              const float* __restrict__ disg, const uint2* __restrict__ xwh,
              const float* __restrict__ bias, float4* __restrict__ out4,
              int E, int NB1, int NBUCK, int N) {
    __shared__ int lh[BW], stt[BW], cur[BW];
    __shared__ int srtL[CAP];
    __shared__ int wsum[4];
    int b = blockIdx.x;
    int tid = threadIdx.x;
    if (tid < BW) lh[tid] = 0;
    __syncthreads();
    int lo = histS[b * NB1];
    int hi = (b == NBUCK - 1) ? E : histS[(b + 1) * NB1];
    int sz = min(hi - lo, CAP);
    const int* pk = packed + lo;
    for (int i = tid; i < sz; i += 1024)
        atomicAdd(&lh[pk[i] & 255], 1);
    __syncthreads();
    int lane = tid & 63, wv4 = tid >> 6;
    int v = (tid < BW) ? lh[tid] : 0;
    int s = v;
#pragma unroll
    for (int off = 1; off < 64; off <<= 1) {
        int u = __shfl_up(s, off);
        if (lane >= off) s += u;
    }
    if (tid < BW && lane == 63) wsum[wv4] = s;
    __syncthreads();
    if (tid < BW) {
        int woff = 0;
        for (int w = 0; w < 4; ++w) woff += (w < wv4) ? wsum[w] : 0;
        int st = woff + s - v;
        stt[tid] = st;
        cur[tid] = st;
    }
    __syncthreads();
    for (int i = tid; i < sz; i += 1024) {
        int p = pk[i];
        int pos = atomicAdd(&cur[p & 255], 1);   // LDS only
        srtL[pos] = p >> 8;
    }
    __syncthreads();
    int wv = tid >> 6;
    int q = lane >> 4;       // edge subset 0..3
    int l = lane & 15;       // 8-byte chunk: dims 4l..4l+3
    const float4 bb = ((const float4*)bias)[l];
#define ADDS(h, ww)                                                         \
    {                                                                       \
        __half2 h0 = *(__half2*)&(h).x, h1 = *(__half2*)&(h).y;             \
        float2 f0 = __half22float2(h0), f1 = __half22float2(h1);            \
        acc.x = fmaf((ww), f0.x, acc.x); acc.y = fmaf((ww), f0.y, acc.y);   \
        acc.z = fmaf((ww), f1.x, acc.z); acc.w = fmaf((ww), f1.y, acc.w);   \
    }
    for (int nn = wv * 16; nn < wv * 16 + 16; ++nn) {
        int node = b * BW + nn;
        if (node >= N) break;
        int k = lh[nn], s0 = stt[nn];
        float dn = rsqrtf((float)(k + 1));
        float4 acc = make_float4(0.f, 0.f, 0.f, 0.f);
        if (q == 0) {   // self-loop: contributes dn*xw[c]; final scale by dn
            uint2 hs = xwh[(size_t)node * 16 + l];
            ADDS(hs, dn);
        }
        int j = q;
        for (; j + 12 < k; j += 16) {
            int r0 = srtL[s0 + j];
            int r1 = srtL[s0 + j + 4];
            int r2 = srtL[s0 + j + 8];
            int r3 = srtL[s0 + j + 12];
            float w0 = disg[r0], w1 = disg[r1], w2 = disg[r2], w3 = disg[r3];
            uint2 va = xwh[(size_t)r0 * 16 + l];
            uint2 vb = xwh[(size_t)r1 * 16 + l];
            uint2 vc = xwh[(size_t)r2 * 16 + l];
            uint2 vd = xwh[(size_t)r3 * 16 + l];
            ADDS(va, w0); ADDS(vb, w1); ADDS(vc, w2); ADDS(vd, w3);
        }
        for (; j < k; j += 4) {
            int r = srtL[s0 + j];
            float wr = disg[r];
            uint2 ve = xwh[(size_t)r * 16 + l];
            ADDS(ve, wr);
        }
#pragma unroll
        for (int mm = 16; mm < 64; mm <<= 1) {
            acc.x += __shfl_xor(acc.x, mm);
            acc.y += __shfl_xor(acc.y, mm);
            acc.z += __shfl_xor(acc.z, mm);
            acc.w += __shfl_xor(acc.w, mm);
        }
        if (q == 0) {
            float4 o;
            o.x = fmaxf(fmaf(dn, acc.x, bb.x), 0.f);
            o.y = fmaxf(fmaf(dn, acc.y, bb.y), 0.f);
            o.z = fmaxf(fmaf(dn, acc.z, bb.z), 0.f);
            o.w = fmaxf(fmaf(dn, acc.w, bb.w), 0.f);
            out4[(size_t)node * 16 + l] = o;
        }
    }
#undef ADDS
}

extern "C" void kernel_launch(void* const* d_in, const int* in_sizes, int n_in,
                              void* d_out, int out_size, void* d_ws, size_t ws_size,
                              hipStream_t stream) {
    const float* x    = (const float*)d_in[0];
    const int*   ei   = (const int*)d_in[1];   // int32 (JAX demotes int64)
    const float* W    = (const float*)d_in[2];
    const float* bias = (const float*)d_in[3];
    float* out = (float*)d_out;

    const int N = in_sizes[0] / D;
    const int E = in_sizes[1] / 2;
    const int* row = ei;       // edge_index[0] = sources
    const int* col = ei + E;   // edge_index[1] = destinations

    const int NBUCK = (N + BW - 1) / BW;        // 391
    const int NB1   = (E + EPB - 1) / EPB;      // 391
    const int L     = NBUCK * NB1;              // 152,881
    const int P     = (L + SCAN_CHUNK - 1) / SCAN_CHUNK;  // 150
    const int NT    = (N + 15) / 16;            // 6250 M-tiles

    char* ws = (char*)d_ws;
    size_t off = 0;
    unsigned short* xw_h = (unsigned short*)(ws + off);
    off += (size_t)N * D * sizeof(unsigned short);                       // 12.8 MB
    int*   packed  = (int*)(ws + off);   off += (size_t)E * sizeof(int); // 6.4 MB
    int*   hist    = (int*)(ws + off);   off += (size_t)L * sizeof(int);
    int*   histS   = (int*)(ws + off);   off += (size_t)L * sizeof(int);
    float* disg    = (float*)(ws + off); off += (size_t)N * sizeof(float);
    int*   partial = (int*)(ws + off);   off += 256 * sizeof(int);

    size_t lds1 = (size_t)NBUCK * sizeof(int);

    k_gemm<<<(NT + 3) / 4, 256, 0, stream>>>(x, W, xw_h, N);
    k_hist1<<<NB1, PART_T, lds1, stream>>>(col, hist, E, NB1, NBUCK);
    k_blocksum<<<P, 256, 0, stream>>>(hist, partial, L);
    k_scan_partials<<<1, 256, 0, stream>>>(partial, P);
    k_scan_excl<<<P, 256, 0, stream>>>(hist, partial, histS, L);
    k_scatter1<<<NB1, PART_T, lds1, stream>>>(row, col, histS, packed, E, NB1, NBUCK);
    k_dis<<<NBUCK, BW, 0, stream>>>(histS, packed, disg, E, NB1, NBUCK, N);
    k_gather<<<NBUCK, 1024, 0, stream>>>(histS, packed, disg, (const uint2*)xw_h,
                                         bias, (float4*)out, E, NB1, NBUCK, N);
}